// Round 15
// baseline (211.062 us; speedup 1.0000x reference)
//
#include <hip/hip_runtime.h>

#define NPATH  2048
#define DIM    64
#define NSTEPS 500
#define PPW    16   // paths per tile (one block per tile, 4 waves)

typedef __attribute__((ext_vector_type(8))) short bf16x8;
typedef __attribute__((ext_vector_type(4))) float f32x4;

union FragU { bf16x8 v; unsigned int u[4]; uint4 q; };

__device__ __forceinline__ unsigned int pk_bf16(float lo, float hi) {
    unsigned int r;
    asm("v_cvt_pk_bf16_f32 %0, %1, %2" : "=v"(r) : "v"(lo), "v"(hi));
    return r;
}

#define MFMA __builtin_amdgcn_mfma_f32_16x16x32_bf16

// r12 structure (verified 138us) with register demand squeezed under the
// allocator's observed 64-reg target (r13/r14 lesson: inline-asm loads +
// spills are unsound; r12's residue theory: in-loop spill reloads).
// One block = one 16-path tile, 4 waves; wave wn owns output dims
// [16wn,16wn+16). Matrix frags in VGPRs (16); state tile xt bf16 in LDS,
// ping-pong, XOR-swizzled; one raw barrier per step, lgkmcnt-only drain
// (dW ring never vmcnt-drained by us; compiler manages vmem waits).
// Demand cuts vs r12: ring 8->4 (-16), pointers->32-bit offsets (-8),
// bias vectors->post-MFMA scalar adds (-6, matches reference association).
__global__ __launch_bounds__(256, 1) void sde_mfma_sq_kernel(
    const float* __restrict__ x0,
    const float* __restrict__ dW,
    const float* __restrict__ drift,
    const float* __restrict__ drift_bias,
    const float* __restrict__ diffusion,
    const float* __restrict__ diffusion_bias,
    const float* __restrict__ ts,
    float* __restrict__ out)
{
    __shared__ __align__(16) unsigned short xt[2][PPW * DIM];  // bf16, swizzled
    __shared__ float2 dtp[NSTEPS + 1];

    const int tid   = threadIdx.x;
    const int wn    = tid >> 6;          // wave = output-dim quarter
    const int lane  = tid & 63;
    const int c     = lane & 15;
    const int h     = lane >> 4;
    const int pbase = blockIdx.x * PPW;
    const int mydim = 16 * wn + c;

    for (int i = tid; i < NSTEPS; i += 256) {
        const float d = ts[i + 1] - ts[i];          // f32-exact vs reference
        dtp[i] = make_float2(d, sqrtf(d));
    }
    if (tid == 0) dtp[NSTEPS] = make_float2(0.f, 0.f);

    // B-frags for this wave's quarter (verified k-packing: lane (c,h) holds
    // M[mydim][32*kk + 8*h + e], e=0..7, matching the A-side packing)
    FragU bd0, bd1, bs0, bs1;
    {
        const float* Ar = drift     + mydim * DIM + 8 * h;
        const float* Cr = diffusion + mydim * DIM + 8 * h;
        float4 t;
        t = *(const float4*)(Ar +  0); bd0.u[0] = pk_bf16(t.x, t.y); bd0.u[1] = pk_bf16(t.z, t.w);
        t = *(const float4*)(Ar +  4); bd0.u[2] = pk_bf16(t.x, t.y); bd0.u[3] = pk_bf16(t.z, t.w);
        t = *(const float4*)(Ar + 32); bd1.u[0] = pk_bf16(t.x, t.y); bd1.u[1] = pk_bf16(t.z, t.w);
        t = *(const float4*)(Ar + 36); bd1.u[2] = pk_bf16(t.x, t.y); bd1.u[3] = pk_bf16(t.z, t.w);
        t = *(const float4*)(Cr +  0); bs0.u[0] = pk_bf16(t.x, t.y); bs0.u[1] = pk_bf16(t.z, t.w);
        t = *(const float4*)(Cr +  4); bs0.u[2] = pk_bf16(t.x, t.y); bs0.u[3] = pk_bf16(t.z, t.w);
        t = *(const float4*)(Cr + 32); bs1.u[0] = pk_bf16(t.x, t.y); bs1.u[1] = pk_bf16(t.z, t.w);
        t = *(const float4*)(Cr + 36); bs1.u[2] = pk_bf16(t.x, t.y); bs1.u[3] = pk_bf16(t.z, t.w);
    }
    const float bdr = drift_bias[mydim];        // scalar biases: added post-MFMA
    const float bdi = diffusion_bias[mydim];    // (reference association: sum, then +b)
    const f32x4 cz  = {0.f, 0.f, 0.f, 0.f};

    // state (4 paths x this lane's dim), 32-bit offsets, xt write offsets
    float xst[4];
    unsigned int ooff[4];   // out element offset of row 0 for path j
    unsigned int dwoff[4];  // dW element offset of row 0 for path j
    unsigned int woff[4];   // xt halfword write offset
#pragma unroll
    for (int j = 0; j < 4; ++j) {
        const int pp = 4 * h + j;
        const int p  = pbase + pp;
        dwoff[j] = (unsigned)(p * NSTEPS * DIM + mydim);
        ooff[j]  = (unsigned)(p * (NSTEPS + 1) * DIM + mydim);
        woff[j]  = (unsigned)((pp * 32 + ((mydim >> 1) ^ ((pp & 7) << 2))) * 2 + (c & 1));
        const float v = x0[p * DIM + mydim];
        xst[j] = v;
        out[ooff[j]] = v;                               // ys[:,0,:]
        xt[0][woff[j]] = (unsigned short)pk_bf16(v, v); // x tile for step 0
    }

    // step-invariant read offsets (uint4 granularity; swizzle folded in)
    const int ra0 = c * 8 + (h ^ (c & 7));          // dims 8h+0..7   of path c
    const int ra1 = c * 8 + ((4 + h) ^ (c & 7));    // dims 32+8h+0..7
    const uint4* xr0 = (const uint4*)xt[0];
    const uint4* xr1 = (const uint4*)xt[1];
    unsigned short* xw0 = xt[0];
    unsigned short* xw1 = xt[1];

    // dW ring, depth 4 (named rings, static indices only)
    float R0[4], R1[4], R2[4], R3[4];
#pragma unroll
    for (int j = 0; j < 4; ++j) {
        R0[j] = dW[dwoff[j] + 0 * DIM];
        R1[j] = dW[dwoff[j] + 1 * DIM];
        R2[j] = dW[dwoff[j] + 2 * DIM];
        R3[j] = dW[dwoff[j] + 3 * DIM];
    }

    __syncthreads();                     // one-time full sync (xt[0], dtp ready)

    float2 dts = dtp[0];                 // {dt, sdt} current step
    const float2* pdt = &dtp[1];         // next step's pair
    unsigned int uo = DIM;               // out row offset (row S+1), uniform
    unsigned int up = 4 * DIM;           // dW prefetch row offset (step S+4)

#define STEP(R, PF, XR, XW)                                                   \
    {                                                                         \
        FragU a0, a1;                                                         \
        a0.q = XR[ra0];                                                       \
        a1.q = XR[ra1];                                                       \
        const float srw0 = dts.y * R[0];  /* consume ring before refill */    \
        const float srw1 = dts.y * R[1];                                      \
        const float srw2 = dts.y * R[2];                                      \
        const float srw3 = dts.y * R[3];                                      \
        if (PF) {                                                             \
            R[0] = dW[dwoff[0] + up];                                         \
            R[1] = dW[dwoff[1] + up];                                         \
            R[2] = dW[dwoff[2] + up];                                         \
            R[3] = dW[dwoff[3] + up];                                         \
        }                                                                     \
        const float2 dtn = *pdt++;                                            \
        const f32x4 adA = MFMA(a0.v, bd0.v, cz, 0, 0, 0);                     \
        const f32x4 adB = MFMA(a1.v, bd1.v, cz, 0, 0, 0);                     \
        const f32x4 ciA = MFMA(a0.v, bs0.v, cz, 0, 0, 0);                     \
        const f32x4 ciB = MFMA(a1.v, bs1.v, cz, 0, 0, 0);                     \
        const float srw[4] = {srw0, srw1, srw2, srw3};                        \
        _Pragma("unroll")                                                     \
        for (int j = 0; j < 4; ++j) {                                         \
            const float ad = (adA[j] + adB[j]) + bdr;                         \
            const float ci = (ciA[j] + ciB[j]) + bdi;                         \
            const float xn = fmaf(dts.x, ad, xst[j]) + ci * srw[j];           \
            xst[j] = xn;                                                      \
            __builtin_nontemporal_store(xn, out + (ooff[j] + uo));            \
            XW[woff[j]] = (unsigned short)pk_bf16(xn, xn);                    \
        }                                                                     \
        uo += DIM;                                                            \
        up += DIM;                                                            \
        dts = dtn;                                                            \
        asm volatile("s_waitcnt lgkmcnt(0)" ::: "memory");                    \
        __builtin_amdgcn_s_barrier();                                         \
        __builtin_amdgcn_sched_barrier(0);                                    \
    }

    // main loop: 124 groups of 4 = steps 0..495, refilling steps 4..499
    for (int it = 0; it < NSTEPS / 4 - 1; ++it) {
        STEP(R0, 1, xr0, xw1)
        STEP(R1, 1, xr1, xw0)
        STEP(R2, 1, xr0, xw1)
        STEP(R3, 1, xr1, xw0)
    }
    // tail: steps 496..499, no refill
    {
        STEP(R0, 0, xr0, xw1)
        STEP(R1, 0, xr1, xw0)
        STEP(R2, 0, xr0, xw1)
        STEP(R3, 0, xr1, xw0)
    }
#undef STEP
}

extern "C" void kernel_launch(void* const* d_in, const int* in_sizes, int n_in,
                              void* d_out, int out_size, void* d_ws, size_t ws_size,
                              hipStream_t stream) {
    const float* x0             = (const float*)d_in[0];
    const float* dW             = (const float*)d_in[1];
    const float* drift          = (const float*)d_in[2];
    const float* drift_bias     = (const float*)d_in[3];
    const float* diffusion      = (const float*)d_in[4];
    const float* diffusion_bias = (const float*)d_in[5];
    const float* ts             = (const float*)d_in[6];
    float* out = (float*)d_out;

    dim3 grid(NPATH / PPW);   // 128 blocks (one 16-path tile each)
    dim3 block(256);          // 4 waves
    hipLaunchKernelGGL(sde_mfma_sq_kernel, grid, block, 0, stream,
                       x0, dW, drift, drift_bias, diffusion, diffusion_bias,
                       ts, out);
}